// Round 1
// baseline (132.289 us; speedup 1.0000x reference)
//
#include <hip/hip_runtime.h>

// EdgeTypeGNNLayer on MI355X — atomic-append TYPE-SPLIT bucketing + fused
// accum+MFMA, bf16 X gather (L2-resident).
//
//   row(n) = [ sum_{e:type0,dst=n} Xb[src] | sum_{e:type1} Xb[src] | Xb[n] ]
//   out    = relu(row @ [Wd|Wc|Ws].T + c0*bd + c1*bc + bs)        fp32
//
// R6: phase 1 was VALU-issue-bound (~10 wave-issues/edge: masked FMAs +
// type unpack + n0 count, 2 edges/wave). Split buckets by edge type at
// append time -> phase 1 is pure adds, no masks; 16-lane groups with
// 8 comps/lane (dwordx4 gather, 4 edges in flight per wave, ~5.3
// issues/edge). Two groups per node: one per type list. Phase 2 unchanged.

#define IN_DIM 128
#define K_CAT  384
#define CAP    256     // per-type bucket capacity; per-type degree ~Poisson(32)
#define CSTR   16      // counter stride in ints: one 64B line per node
                       //   cnt[d*16+0] = type0 count, cnt[d*16+8] = type1
#define ROWP   392     // padded LDS row length in shorts (384+8): row stride
                       // 784B -> b128 reads spread all 32 banks

typedef short short8  __attribute__((ext_vector_type(8)));
typedef unsigned short ushortx8 __attribute__((ext_vector_type(8)));
typedef float floatx4 __attribute__((ext_vector_type(4)));

#define NW_ITEMS (8 * 12 * 64)      // WB short8 items

__device__ inline unsigned short f2bf(float f) {
    unsigned u = __float_as_uint(f);
    u += 0x7FFF + ((u >> 16) & 1);          // RNE
    return (unsigned short)(u >> 16);
}

// One kernel, three independent jobs (grid-strided virtual index):
//  [0, NW)            : build WB in MFMA B-fragment order
//  [NW, NW+NX)        : convert X fp32 -> bf16 (float4 -> ushort4)
//  [NW+NX, NW+NX+NC)  : zero cnt (int4)
__global__ __launch_bounds__(256) void prep_kernel(
    const float* __restrict__ X,
    const float* __restrict__ Wd, const float* __restrict__ Wc,
    const float* __restrict__ Ws,
    unsigned short* __restrict__ WB,
    unsigned short* __restrict__ Xb,
    int* __restrict__ cnt, int N)
{
    const int NX = N * 32;          // float4 items of X
    const int NC = N * CSTR / 4;    // int4 items of cnt
    int idx = blockIdx.x * 256 + threadIdx.x;

    if (idx < NW_ITEMS) {
        // WB[(nt*12 + kt)*64 + lane]: lane's short8 for n-tile nt, k-step kt
        //   col = nt*16 + (lane&15), k = kt*32 + (lane>>4)*8 + j
        int lane = idx & 63;
        int kt   = (idx >> 6) % 12;
        int nt   = idx / (64 * 12);
        int col  = nt * 16 + (lane & 15);
        int kb   = kt * 32 + (lane >> 4) * 8;
        unsigned short v[8];
        #pragma unroll
        for (int j = 0; j < 8; j++) {
            int k = kb + j;
            float w = (k < 128) ? Wd[col * 128 + k]
                    : (k < 256) ? Wc[col * 128 + (k - 128)]
                                : Ws[col * 128 + (k - 256)];
            v[j] = f2bf(w);
        }
        *(short8*)(WB + (size_t)idx * 8) = *(short8*)v;
        return;
    }
    idx -= NW_ITEMS;
    if (idx < NX) {
        float4 v = ((const float4*)X)[idx];
        ushort4 o;
        o.x = f2bf(v.x); o.y = f2bf(v.y); o.z = f2bf(v.z); o.w = f2bf(v.w);
        ((ushort4*)Xb)[idx] = o;
        return;
    }
    idx -= NX;
    if (idx < NC) {
        ((int4*)cnt)[idx] = make_int4(0, 0, 0, 0);
    }
}

// 4 edges per thread, vectorized index reads. Entry = bare src id (16 bit),
// routed to bucket0 or bucket1 by edge type.
__global__ __launch_bounds__(256) void append_kernel(
    const int* __restrict__ src,
    const int* __restrict__ dst,
    const int* __restrict__ etype,
    int* __restrict__ cnt,
    unsigned short* __restrict__ b0,
    unsigned short* __restrict__ b1, int E)
{
    int e0 = (blockIdx.x * 256 + threadIdx.x) * 4;

#define PUT(SS, DD, TT) do {                                             \
        int _d = (DD); int _t = (TT);                                    \
        unsigned short* _b = _t ? b1 : b0;                               \
        int _pos = atomicAdd(&cnt[_d * CSTR + (_t << 3)], 1);            \
        if (_pos < CAP)                                                  \
            _b[(size_t)_d * CAP + _pos] = (unsigned short)(SS);          \
    } while (0)

    if (e0 + 4 <= E) {
        int4 s = *(const int4*)(src + e0);
        int4 d = *(const int4*)(dst + e0);
        int4 t = *(const int4*)(etype + e0);
        PUT(s.x, d.x, t.x);
        PUT(s.y, d.y, t.y);
        PUT(s.z, d.z, t.z);
        PUT(s.w, d.w, t.w);
    } else {
        for (int e = e0; e < E; e++)
            PUT(src[e], dst[e], etype[e]);
    }
#undef PUT
}

// Block = 512 threads. Phase 1: 32 groups of 16 lanes; group (hw,h) walks
// node hw's type-h list (disjoint lists -> no masking, no reduction across
// groups). Lane q owns comps [q*8, q*8+8): dwordx4 gather of bf16 X,
// fp32 adds, bf16 LDS row write. Phase 2 (unchanged): 8 waves, wave w =
// n-tile w, K=384 in 12 MFMA steps; A from LDS (ds_read_b128), B coalesced
// from fragment-ordered WB.
// Frag layouts (m89/m120-verified):
//   A: lane holds A[m=lane&15][kt*32 + (lane>>4)*8 ..+7]
//   B: lane holds B[k][n=lane&15]
//   D: lane reg r -> C[row=(lane>>4)*4 + r][col=lane&15]
__global__ __launch_bounds__(512) void fused_kernel(
    const unsigned short* __restrict__ Xb,
    const int* __restrict__ cnt,
    const unsigned short* __restrict__ bucket0,
    const unsigned short* __restrict__ bucket1,
    const unsigned short* __restrict__ WB,
    const float* __restrict__ bd, const float* __restrict__ bc,
    const float* __restrict__ bs,
    float* __restrict__ out, int N)
{
    __shared__ unsigned short Als[16][ROWP];   // 12.25 KB, rows 16B-aligned
    __shared__ float lc0[16], lc1[16];

    const int tid = threadIdx.x;
    const int m0  = blockIdx.x * 16;

    // ---------- phase 1: accumulate (type-split, maskless) ----------
    {
        const int hw2 = tid >> 4;        // group 0..31
        const int hw  = hw2 >> 1;        // node slot 0..15
        const int h   = hw2 & 1;         // type list 0/1
        const int q   = tid & 15;        // comp block: comps [q*8, q*8+8)
        const int d   = m0 + hw;
        if (d < N) {
            const uint4* Xr = (const uint4*)Xb;   // row = 16 uint4 (256 B)
            int len = cnt[d * CSTR + (h << 3)];
            if (len > CAP) len = CAP;
            const unsigned short* bl =
                (h ? bucket1 : bucket0) + (size_t)d * CAP;

            float a[8];
            #pragma unroll
            for (int j = 0; j < 8; j++) a[j] = 0.f;

#define ACC(S) do {                                                      \
            int _s = (int)(S);                                           \
            uint4 _u = Xr[_s * 16 + q];                                  \
            a[0] += __uint_as_float(_u.x << 16);                         \
            a[1] += __uint_as_float(_u.x & 0xFFFF0000u);                 \
            a[2] += __uint_as_float(_u.y << 16);                         \
            a[3] += __uint_as_float(_u.y & 0xFFFF0000u);                 \
            a[4] += __uint_as_float(_u.z << 16);                         \
            a[5] += __uint_as_float(_u.z & 0xFFFF0000u);                 \
            a[6] += __uint_as_float(_u.w << 16);                         \
            a[7] += __uint_as_float(_u.w & 0xFFFF0000u);                 \
        } while (0)
#define ACC8(PP) do {                                                    \
            ACC((PP).x & 0xFFFF); ACC((PP).x >> 16);                     \
            ACC((PP).y & 0xFFFF); ACC((PP).y >> 16);                     \
            ACC((PP).z & 0xFFFF); ACC((PP).z >> 16);                     \
            ACC((PP).w & 0xFFFF); ACC((PP).w >> 16);                     \
        } while (0)

            int i = 0;
            for (; i + 16 <= len; i += 16) {       // 16 gathers in flight
                uint4 p0 = *(const uint4*)(bl + i);
                uint4 p1 = *(const uint4*)(bl + i + 8);
                ACC8(p0); ACC8(p1);
            }
            for (; i + 8 <= len; i += 8) {
                uint4 p0 = *(const uint4*)(bl + i);
                ACC8(p0);
            }
            for (; i < len; i++) ACC(bl[i]);
#undef ACC8
#undef ACC

            unsigned short* row = &Als[hw][0];
            ushortx8 o;
            #pragma unroll
            for (int j = 0; j < 8; j++) o[j] = f2bf(a[j]);
            *(ushortx8*)(row + h * 128 + q * 8) = o;   // b128, 16B-aligned

            if (h == 0) {                               // self row passthrough
                uint4 su = Xr[d * 16 + q];
                *(uint4*)(row + 256 + q * 8) = su;
            }
            if (q == 0) {
                if (h == 0) lc0[hw] = (float)len;
                else        lc1[hw] = (float)len;
            }
        }
    }
    __syncthreads();

    // ---------- phase 2: MFMA gemm (unchanged) ----------
    const int wave = tid >> 6;          // n-tile (0..7)
    const int lane = tid & 63;
    const int rA   = lane & 15;
    const int quad = lane >> 4;

    floatx4 acc = (floatx4){0.f, 0.f, 0.f, 0.f};
    const short8* B8 = (const short8*)WB + (size_t)wave * 12 * 64 + lane;

    #pragma unroll
    for (int kt = 0; kt < 12; kt++) {
        short8 a = *(const short8*)&Als[rA][kt * 32 + quad * 8];
        short8 b = B8[kt * 64];
        acc = __builtin_amdgcn_mfma_f32_16x16x32_bf16(a, b, acc, 0, 0, 0);
    }

    const int col = wave * 16 + rA;
    const float bdv = bd[col], bcv = bc[col], bsv = bs[col];
    #pragma unroll
    for (int r = 0; r < 4; r++) {
        int lrow = quad * 4 + r;
        int grow = m0 + lrow;
        if (grow < N) {
            float v = acc[r] + lc0[lrow] * bdv + lc1[lrow] * bcv + bsv;
            out[(size_t)grow * 128 + col] = fmaxf(v, 0.f);
        }
    }
}

extern "C" void kernel_launch(void* const* d_in, const int* in_sizes, int n_in,
                              void* d_out, int out_size, void* d_ws, size_t ws_size,
                              hipStream_t stream) {
    const float* X  = (const float*)d_in[0];
    const int*   ei = (const int*)d_in[1];    // [src(E) | dst(E)]
    const int*   et = (const int*)d_in[2];
    const float* Wd = (const float*)d_in[3];
    const float* bd = (const float*)d_in[4];
    const float* Wc = (const float*)d_in[5];
    const float* bc = (const float*)d_in[6];
    const float* Ws = (const float*)d_in[7];
    const float* bs = (const float*)d_in[8];
    float* out = (float*)d_out;

    const int N = in_sizes[0] / IN_DIM;       // 10000
    const int E = in_sizes[2];                // 640000

    // workspace layout (16B-aligned sections)
    unsigned short* WB  = (unsigned short*)d_ws;              // 8*12*64*8 bf16
    unsigned short* Xb  = WB + (size_t)NW_ITEMS * 8;          // N*128 bf16
    unsigned short* b0  = Xb + (size_t)N * IN_DIM;            // N*CAP ushort
    unsigned short* b1  = b0 + (size_t)N * CAP;               // N*CAP ushort
    int*            cnt = (int*)(b1 + (size_t)N * CAP);       // N*CSTR ints

    const int* src = ei;
    const int* dst = ei + E;

    int prep_items = NW_ITEMS + N * 32 + N * CSTR / 4;
    prep_kernel<<<(prep_items + 255) / 256, 256, 0, stream>>>(
        X, Wd, Wc, Ws, WB, Xb, cnt, N);

    int eb = (E / 4 + 255) / 256;
    append_kernel<<<eb, 256, 0, stream>>>(src, dst, et, cnt, b0, b1, E);

    int fb = (N + 15) / 16;
    fused_kernel<<<fb, 512, 0, stream>>>(Xb, cnt, b0, b1, WB, bd, bc, bs, out, N);
}

// Round 2
// 128.797 us; speedup vs baseline: 1.0271x; 1.0271x over previous
//
#include <hip/hip_runtime.h>

// EdgeTypeGNNLayer on MI355X — atomic-append TYPE-SPLIT bucketing + fused
// accum+MFMA, bf16 X gather (L2-resident).
//
//   row(n) = [ sum_{e:type0,dst=n} Xb[src] | sum_{e:type1} Xb[src] | Xb[n] ]
//   out    = relu(row @ [Wd|Wc|Ws].T + c0*bd + c1*bc + bs)        fp32
//
// R7: R6's phase-1 restructure (2x fewer VALU issues) was NEUTRAL -> phase 1
// was never the bound (arith: ~4 us chip-wide). Remaining own-cost structure:
// dispatch-chain serialization (prep -> append -> fused, append waits on all
// of prep). Fix: cnt zeroed via hipMemsetAsync (capturable), append MERGED
// into prep as one kernel (append blocks first -> atomic/scatter latency
// overlaps Xb-conversion bandwidth). 3 kernels + memset -> 2 kernels + memset,
// and append leaves the serial critical path.

#define IN_DIM 128
#define K_CAT  384
#define CAP    256     // per-type bucket capacity; per-type degree ~Poisson(32)
#define CSTR   16      // counter stride in ints: one 64B line per node
                       //   cnt[d*16+0] = type0 count, cnt[d*16+8] = type1
#define ROWP   392     // padded LDS row length in shorts (384+8): row stride
                       // 784B -> b128 reads spread banks

typedef short short8  __attribute__((ext_vector_type(8)));
typedef unsigned short ushortx8 __attribute__((ext_vector_type(8)));
typedef float floatx4 __attribute__((ext_vector_type(4)));

#define NW_ITEMS (8 * 12 * 64)      // WB short8 items

__device__ inline unsigned short f2bf(float f) {
    unsigned u = __float_as_uint(f);
    u += 0x7FFF + ((u >> 16) & 1);          // RNE
    return (unsigned short)(u >> 16);
}

// One kernel, three independent jobs (virtual index ranges):
//  [0, NE)            : append 4 edges/thread into type-split buckets
//  [NE, NE+NW)        : build WB in MFMA B-fragment order
//  [NE+NW, NE+NW+NX)  : convert X fp32 -> bf16 (float4 -> ushort4)
// cnt is pre-zeroed by hipMemsetAsync on the stream (graph-capturable).
// Append blocks are placed FIRST so their atomic/scatter latency overlaps
// the Xb conversion blocks' bandwidth phase.
__global__ __launch_bounds__(256) void build_kernel(
    const float* __restrict__ X,
    const float* __restrict__ Wd, const float* __restrict__ Wc,
    const float* __restrict__ Ws,
    const int* __restrict__ src,
    const int* __restrict__ dst,
    const int* __restrict__ etype,
    int* __restrict__ cnt,
    unsigned short* __restrict__ b0,
    unsigned short* __restrict__ b1,
    unsigned short* __restrict__ WB,
    unsigned short* __restrict__ Xb,
    int N, int E)
{
    const int NE = E / 4;           // 4 edges per append thread (E % 4 == 0)
    const int NX = N * 32;          // float4 items of X
    int idx = blockIdx.x * 256 + threadIdx.x;

    if (idx < NE) {
        int e0 = idx * 4;
        int4 s = *(const int4*)(src + e0);
        int4 d = *(const int4*)(dst + e0);
        int4 t = *(const int4*)(etype + e0);
#define PUT(SS, DD, TT) do {                                             \
        int _d = (DD); int _t = (TT);                                    \
        unsigned short* _b = _t ? b1 : b0;                               \
        int _pos = atomicAdd(&cnt[_d * CSTR + (_t << 3)], 1);            \
        if (_pos < CAP)                                                  \
            _b[(size_t)_d * CAP + _pos] = (unsigned short)(SS);          \
    } while (0)
        PUT(s.x, d.x, t.x);
        PUT(s.y, d.y, t.y);
        PUT(s.z, d.z, t.z);
        PUT(s.w, d.w, t.w);
#undef PUT
        return;
    }
    idx -= NE;
    if (idx < NW_ITEMS) {
        // WB[(nt*12 + kt)*64 + lane]: lane's short8 for n-tile nt, k-step kt
        //   col = nt*16 + (lane&15), k = kt*32 + (lane>>4)*8 + j
        int lane = idx & 63;
        int kt   = (idx >> 6) % 12;
        int nt   = idx / (64 * 12);
        int col  = nt * 16 + (lane & 15);
        int kb   = kt * 32 + (lane >> 4) * 8;
        unsigned short v[8];
        #pragma unroll
        for (int j = 0; j < 8; j++) {
            int k = kb + j;
            float w = (k < 128) ? Wd[col * 128 + k]
                    : (k < 256) ? Wc[col * 128 + (k - 128)]
                                : Ws[col * 128 + (k - 256)];
            v[j] = f2bf(w);
        }
        *(short8*)(WB + (size_t)idx * 8) = *(short8*)v;
        return;
    }
    idx -= NW_ITEMS;
    if (idx < NX) {
        float4 v = ((const float4*)X)[idx];
        ushort4 o;
        o.x = f2bf(v.x); o.y = f2bf(v.y); o.z = f2bf(v.z); o.w = f2bf(v.w);
        ((ushort4*)Xb)[idx] = o;
    }
}

// Block = 512 threads. Phase 1: 32 groups of 16 lanes; group (hw,h) walks
// node hw's type-h list (disjoint lists -> no masking). Lane q owns comps
// [q*8, q*8+8): dwordx4 gather of bf16 X, fp32 adds, bf16 LDS row write.
// Phase 2: 8 waves, wave w = n-tile w, K=384 in 12 MFMA steps; A from LDS
// (ds_read_b128), B coalesced from fragment-ordered WB.
// Frag layouts (m89/m120-verified):
//   A: lane holds A[m=lane&15][kt*32 + (lane>>4)*8 ..+7]
//   B: lane holds B[k][n=lane&15]
//   D: lane reg r -> C[row=(lane>>4)*4 + r][col=lane&15]
__global__ __launch_bounds__(512) void fused_kernel(
    const unsigned short* __restrict__ Xb,
    const int* __restrict__ cnt,
    const unsigned short* __restrict__ bucket0,
    const unsigned short* __restrict__ bucket1,
    const unsigned short* __restrict__ WB,
    const float* __restrict__ bd, const float* __restrict__ bc,
    const float* __restrict__ bs,
    float* __restrict__ out, int N)
{
    __shared__ unsigned short Als[16][ROWP];   // 12.25 KB, rows 16B-aligned
    __shared__ float lc0[16], lc1[16];

    const int tid = threadIdx.x;
    const int m0  = blockIdx.x * 16;

    // ---------- phase 1: accumulate (type-split, maskless) ----------
    {
        const int hw2 = tid >> 4;        // group 0..31
        const int hw  = hw2 >> 1;        // node slot 0..15
        const int h   = hw2 & 1;         // type list 0/1
        const int q   = tid & 15;        // comp block: comps [q*8, q*8+8)
        const int d   = m0 + hw;
        if (d < N) {
            const uint4* Xr = (const uint4*)Xb;   // row = 16 uint4 (256 B)
            int len = cnt[d * CSTR + (h << 3)];
            if (len > CAP) len = CAP;
            const unsigned short* bl =
                (h ? bucket1 : bucket0) + (size_t)d * CAP;

            float a[8];
            #pragma unroll
            for (int j = 0; j < 8; j++) a[j] = 0.f;

#define ACC(S) do {                                                      \
            int _s = (int)(S);                                           \
            uint4 _u = Xr[_s * 16 + q];                                  \
            a[0] += __uint_as_float(_u.x << 16);                         \
            a[1] += __uint_as_float(_u.x & 0xFFFF0000u);                 \
            a[2] += __uint_as_float(_u.y << 16);                         \
            a[3] += __uint_as_float(_u.y & 0xFFFF0000u);                 \
            a[4] += __uint_as_float(_u.z << 16);                         \
            a[5] += __uint_as_float(_u.z & 0xFFFF0000u);                 \
            a[6] += __uint_as_float(_u.w << 16);                         \
            a[7] += __uint_as_float(_u.w & 0xFFFF0000u);                 \
        } while (0)
#define ACC8(PP) do {                                                    \
            ACC((PP).x & 0xFFFF); ACC((PP).x >> 16);                     \
            ACC((PP).y & 0xFFFF); ACC((PP).y >> 16);                     \
            ACC((PP).z & 0xFFFF); ACC((PP).z >> 16);                     \
            ACC((PP).w & 0xFFFF); ACC((PP).w >> 16);                     \
        } while (0)

            int i = 0;
            for (; i + 16 <= len; i += 16) {       // 16 gathers in flight
                uint4 p0 = *(const uint4*)(bl + i);
                uint4 p1 = *(const uint4*)(bl + i + 8);
                ACC8(p0); ACC8(p1);
            }
            for (; i + 8 <= len; i += 8) {
                uint4 p0 = *(const uint4*)(bl + i);
                ACC8(p0);
            }
            for (; i < len; i++) ACC(bl[i]);
#undef ACC8
#undef ACC

            unsigned short* row = &Als[hw][0];
            ushortx8 o;
            #pragma unroll
            for (int j = 0; j < 8; j++) o[j] = f2bf(a[j]);
            *(ushortx8*)(row + h * 128 + q * 8) = o;   // b128, 16B-aligned

            if (h == 0) {                               // self row passthrough
                uint4 su = Xr[d * 16 + q];
                *(uint4*)(row + 256 + q * 8) = su;
            }
            if (q == 0) {
                if (h == 0) lc0[hw] = (float)len;
                else        lc1[hw] = (float)len;
            }
        }
    }
    __syncthreads();

    // ---------- phase 2: MFMA gemm ----------
    const int wave = tid >> 6;          // n-tile (0..7)
    const int lane = tid & 63;
    const int rA   = lane & 15;
    const int quad = lane >> 4;

    floatx4 acc = (floatx4){0.f, 0.f, 0.f, 0.f};
    const short8* B8 = (const short8*)WB + (size_t)wave * 12 * 64 + lane;

    #pragma unroll
    for (int kt = 0; kt < 12; kt++) {
        short8 a = *(const short8*)&Als[rA][kt * 32 + quad * 8];
        short8 b = B8[kt * 64];
        acc = __builtin_amdgcn_mfma_f32_16x16x32_bf16(a, b, acc, 0, 0, 0);
    }

    const int col = wave * 16 + rA;
    const float bdv = bd[col], bcv = bc[col], bsv = bs[col];
    #pragma unroll
    for (int r = 0; r < 4; r++) {
        int lrow = quad * 4 + r;
        int grow = m0 + lrow;
        if (grow < N) {
            float v = acc[r] + lc0[lrow] * bdv + lc1[lrow] * bcv + bsv;
            out[(size_t)grow * 128 + col] = fmaxf(v, 0.f);
        }
    }
}

extern "C" void kernel_launch(void* const* d_in, const int* in_sizes, int n_in,
                              void* d_out, int out_size, void* d_ws, size_t ws_size,
                              hipStream_t stream) {
    const float* X  = (const float*)d_in[0];
    const int*   ei = (const int*)d_in[1];    // [src(E) | dst(E)]
    const int*   et = (const int*)d_in[2];
    const float* Wd = (const float*)d_in[3];
    const float* bd = (const float*)d_in[4];
    const float* Wc = (const float*)d_in[5];
    const float* bc = (const float*)d_in[6];
    const float* Ws = (const float*)d_in[7];
    const float* bs = (const float*)d_in[8];
    float* out = (float*)d_out;

    const int N = in_sizes[0] / IN_DIM;       // 10000
    const int E = in_sizes[2];                // 640000

    // workspace layout (16B-aligned sections)
    unsigned short* WB  = (unsigned short*)d_ws;              // 8*12*64*8 bf16
    unsigned short* Xb  = WB + (size_t)NW_ITEMS * 8;          // N*128 bf16
    unsigned short* b0  = Xb + (size_t)N * IN_DIM;            // N*CAP ushort
    unsigned short* b1  = b0 + (size_t)N * CAP;               // N*CAP ushort
    int*            cnt = (int*)(b1 + (size_t)N * CAP);       // N*CSTR ints

    const int* src = ei;
    const int* dst = ei + E;

    // zero bucket counters (640 KB, ~0.1 us) — graph-capturable async memset
    hipMemsetAsync(cnt, 0, (size_t)N * CSTR * sizeof(int), stream);

    int build_items = E / 4 + NW_ITEMS + N * 32;
    build_kernel<<<(build_items + 255) / 256, 256, 0, stream>>>(
        X, Wd, Wc, Ws, src, dst, et, cnt, b0, b1, WB, Xb, N, E);

    int fb = (N + 15) / 16;
    fused_kernel<<<fb, 512, 0, stream>>>(Xb, cnt, b0, b1, WB, bd, bc, bs, out, N);
}

// Round 3
// 128.001 us; speedup vs baseline: 1.0335x; 1.0062x over previous
//
#include <hip/hip_runtime.h>

// EdgeTypeGNNLayer on MI355X — atomic-append TYPE-SPLIT bucketing + fused
// accum+MFMA, bf16 X gather (L2-resident).
//
//   row(n) = [ sum_{e:type0,dst=n} Xb[src] | sum_{e:type1} Xb[src] | Xb[n] ]
//   out    = relu(row @ [Wd|Wc|Ws].T + c0*bd + c1*bc + bs)        fp32
//
// R8: R7 exposed build_kernel at 48.8 us, VALUBusy 0.9%, occ 27% ->
// latency-bound append. Root cause was R6's "4 edges/thread" append: 4x
// fewer waves (625 chip-wide) each chaining 4 dependent atomic->store
// round-trips (~500 cyc each) with no TLP to hide them. Revert to 1
// edge/thread (640k threads, one independent atomic+store each), still
// merged into build (edge blocks first). cnt zeroed via hipMemsetAsync.

#define IN_DIM 128
#define K_CAT  384
#define CAP    256     // per-type bucket capacity; per-type degree ~Poisson(32)
#define CSTR   16      // counter stride in ints: one 64B line per node
                       //   cnt[d*16+0] = type0 count, cnt[d*16+8] = type1
#define ROWP   392     // padded LDS row length in shorts (384+8)

typedef short short8  __attribute__((ext_vector_type(8)));
typedef unsigned short ushortx8 __attribute__((ext_vector_type(8)));
typedef float floatx4 __attribute__((ext_vector_type(4)));

#define NW_ITEMS (8 * 12 * 64)      // WB short8 items

__device__ inline unsigned short f2bf(float f) {
    unsigned u = __float_as_uint(f);
    u += 0x7FFF + ((u >> 16) & 1);          // RNE
    return (unsigned short)(u >> 16);
}

// One kernel, three independent jobs (virtual index ranges):
//  [0, E)             : append 1 edge/thread into type-split buckets
//  [E, E+NW)          : build WB in MFMA B-fragment order
//  [E+NW, E+NW+NX)    : convert X fp32 -> bf16 (float4 -> ushort4)
// cnt is pre-zeroed by hipMemsetAsync on the stream (graph-capturable).
// Append blocks first so their atomic/scatter latency overlaps the Xb
// conversion blocks' bandwidth phase.
__global__ __launch_bounds__(256) void build_kernel(
    const float* __restrict__ X,
    const float* __restrict__ Wd, const float* __restrict__ Wc,
    const float* __restrict__ Ws,
    const int* __restrict__ src,
    const int* __restrict__ dst,
    const int* __restrict__ etype,
    int* __restrict__ cnt,
    unsigned short* __restrict__ b0,
    unsigned short* __restrict__ b1,
    unsigned short* __restrict__ WB,
    unsigned short* __restrict__ Xb,
    int N, int E)
{
    const int NX = N * 32;          // float4 items of X
    int idx = blockIdx.x * 256 + threadIdx.x;

    if (idx < E) {
        int s = src[idx];
        int d = dst[idx];
        int t = etype[idx];
        unsigned short* b = t ? b1 : b0;
        int pos = atomicAdd(&cnt[d * CSTR + (t << 3)], 1);
        if (pos < CAP)
            b[(size_t)d * CAP + pos] = (unsigned short)s;
        return;
    }
    idx -= E;
    if (idx < NW_ITEMS) {
        // WB[(nt*12 + kt)*64 + lane]: lane's short8 for n-tile nt, k-step kt
        //   col = nt*16 + (lane&15), k = kt*32 + (lane>>4)*8 + j
        int lane = idx & 63;
        int kt   = (idx >> 6) % 12;
        int nt   = idx / (64 * 12);
        int col  = nt * 16 + (lane & 15);
        int kb   = kt * 32 + (lane >> 4) * 8;
        unsigned short v[8];
        #pragma unroll
        for (int j = 0; j < 8; j++) {
            int k = kb + j;
            float w = (k < 128) ? Wd[col * 128 + k]
                    : (k < 256) ? Wc[col * 128 + (k - 128)]
                                : Ws[col * 128 + (k - 256)];
            v[j] = f2bf(w);
        }
        *(short8*)(WB + (size_t)idx * 8) = *(short8*)v;
        return;
    }
    idx -= NW_ITEMS;
    if (idx < NX) {
        float4 v = ((const float4*)X)[idx];
        ushort4 o;
        o.x = f2bf(v.x); o.y = f2bf(v.y); o.z = f2bf(v.z); o.w = f2bf(v.w);
        ((ushort4*)Xb)[idx] = o;
    }
}

// Block = 512 threads. Phase 1: 32 groups of 16 lanes; group (hw,h) walks
// node hw's type-h list (disjoint lists -> no masking). Lane q owns comps
// [q*8, q*8+8): dwordx4 gather of bf16 X, fp32 adds, bf16 LDS row write.
// Phase 2: 8 waves, wave w = n-tile w, K=384 in 12 MFMA steps; A from LDS
// (ds_read_b128), B coalesced from fragment-ordered WB.
// Frag layouts (m89/m120-verified):
//   A: lane holds A[m=lane&15][kt*32 + (lane>>4)*8 ..+7]
//   B: lane holds B[k][n=lane&15]
//   D: lane reg r -> C[row=(lane>>4)*4 + r][col=lane&15]
__global__ __launch_bounds__(512) void fused_kernel(
    const unsigned short* __restrict__ Xb,
    const int* __restrict__ cnt,
    const unsigned short* __restrict__ bucket0,
    const unsigned short* __restrict__ bucket1,
    const unsigned short* __restrict__ WB,
    const float* __restrict__ bd, const float* __restrict__ bc,
    const float* __restrict__ bs,
    float* __restrict__ out, int N)
{
    __shared__ unsigned short Als[16][ROWP];   // 12.25 KB, rows 16B-aligned
    __shared__ float lc0[16], lc1[16];

    const int tid = threadIdx.x;
    const int m0  = blockIdx.x * 16;

    // ---------- phase 1: accumulate (type-split, maskless) ----------
    {
        const int hw2 = tid >> 4;        // group 0..31
        const int hw  = hw2 >> 1;        // node slot 0..15
        const int h   = hw2 & 1;         // type list 0/1
        const int q   = tid & 15;        // comp block: comps [q*8, q*8+8)
        const int d   = m0 + hw;
        if (d < N) {
            const uint4* Xr = (const uint4*)Xb;   // row = 16 uint4 (256 B)
            int len = cnt[d * CSTR + (h << 3)];
            if (len > CAP) len = CAP;
            const unsigned short* bl =
                (h ? bucket1 : bucket0) + (size_t)d * CAP;

            float a[8];
            #pragma unroll
            for (int j = 0; j < 8; j++) a[j] = 0.f;

#define ACC(S) do {                                                      \
            int _s = (int)(S);                                           \
            uint4 _u = Xr[_s * 16 + q];                                  \
            a[0] += __uint_as_float(_u.x << 16);                         \
            a[1] += __uint_as_float(_u.x & 0xFFFF0000u);                 \
            a[2] += __uint_as_float(_u.y << 16);                         \
            a[3] += __uint_as_float(_u.y & 0xFFFF0000u);                 \
            a[4] += __uint_as_float(_u.z << 16);                         \
            a[5] += __uint_as_float(_u.z & 0xFFFF0000u);                 \
            a[6] += __uint_as_float(_u.w << 16);                         \
            a[7] += __uint_as_float(_u.w & 0xFFFF0000u);                 \
        } while (0)
#define ACC8(PP) do {                                                    \
            ACC((PP).x & 0xFFFF); ACC((PP).x >> 16);                     \
            ACC((PP).y & 0xFFFF); ACC((PP).y >> 16);                     \
            ACC((PP).z & 0xFFFF); ACC((PP).z >> 16);                     \
            ACC((PP).w & 0xFFFF); ACC((PP).w >> 16);                     \
        } while (0)

            int i = 0;
            for (; i + 16 <= len; i += 16) {       // 16 gathers in flight
                uint4 p0 = *(const uint4*)(bl + i);
                uint4 p1 = *(const uint4*)(bl + i + 8);
                ACC8(p0); ACC8(p1);
            }
            for (; i + 8 <= len; i += 8) {
                uint4 p0 = *(const uint4*)(bl + i);
                ACC8(p0);
            }
            for (; i < len; i++) ACC(bl[i]);
#undef ACC8
#undef ACC

            unsigned short* row = &Als[hw][0];
            ushortx8 o;
            #pragma unroll
            for (int j = 0; j < 8; j++) o[j] = f2bf(a[j]);
            *(ushortx8*)(row + h * 128 + q * 8) = o;   // b128, 16B-aligned

            if (h == 0) {                               // self row passthrough
                uint4 su = Xr[d * 16 + q];
                *(uint4*)(row + 256 + q * 8) = su;
            }
            if (q == 0) {
                if (h == 0) lc0[hw] = (float)len;
                else        lc1[hw] = (float)len;
            }
        }
    }
    __syncthreads();

    // ---------- phase 2: MFMA gemm ----------
    const int wave = tid >> 6;          // n-tile (0..7)
    const int lane = tid & 63;
    const int rA   = lane & 15;
    const int quad = lane >> 4;

    floatx4 acc = (floatx4){0.f, 0.f, 0.f, 0.f};
    const short8* B8 = (const short8*)WB + (size_t)wave * 12 * 64 + lane;

    #pragma unroll
    for (int kt = 0; kt < 12; kt++) {
        short8 a = *(const short8*)&Als[rA][kt * 32 + quad * 8];
        short8 b = B8[kt * 64];
        acc = __builtin_amdgcn_mfma_f32_16x16x32_bf16(a, b, acc, 0, 0, 0);
    }

    const int col = wave * 16 + rA;
    const float bdv = bd[col], bcv = bc[col], bsv = bs[col];
    #pragma unroll
    for (int r = 0; r < 4; r++) {
        int lrow = quad * 4 + r;
        int grow = m0 + lrow;
        if (grow < N) {
            float v = acc[r] + lc0[lrow] * bdv + lc1[lrow] * bcv + bsv;
            out[(size_t)grow * 128 + col] = fmaxf(v, 0.f);
        }
    }
}

extern "C" void kernel_launch(void* const* d_in, const int* in_sizes, int n_in,
                              void* d_out, int out_size, void* d_ws, size_t ws_size,
                              hipStream_t stream) {
    const float* X  = (const float*)d_in[0];
    const int*   ei = (const int*)d_in[1];    // [src(E) | dst(E)]
    const int*   et = (const int*)d_in[2];
    const float* Wd = (const float*)d_in[3];
    const float* bd = (const float*)d_in[4];
    const float* Wc = (const float*)d_in[5];
    const float* bc = (const float*)d_in[6];
    const float* Ws = (const float*)d_in[7];
    const float* bs = (const float*)d_in[8];
    float* out = (float*)d_out;

    const int N = in_sizes[0] / IN_DIM;       // 10000
    const int E = in_sizes[2];                // 640000

    // workspace layout (16B-aligned sections)
    unsigned short* WB  = (unsigned short*)d_ws;              // 8*12*64*8 bf16
    unsigned short* Xb  = WB + (size_t)NW_ITEMS * 8;          // N*128 bf16
    unsigned short* b0  = Xb + (size_t)N * IN_DIM;            // N*CAP ushort
    unsigned short* b1  = b0 + (size_t)N * CAP;               // N*CAP ushort
    int*            cnt = (int*)(b1 + (size_t)N * CAP);       // N*CSTR ints

    const int* src = ei;
    const int* dst = ei + E;

    // zero bucket counters (640 KB) — graph-capturable async memset
    hipMemsetAsync(cnt, 0, (size_t)N * CSTR * sizeof(int), stream);

    int build_items = E + NW_ITEMS + N * 32;
    build_kernel<<<(build_items + 255) / 256, 256, 0, stream>>>(
        X, Wd, Wc, Ws, src, dst, et, cnt, b0, b1, WB, Xb, N, E);

    int fb = (N + 15) / 16;
    fused_kernel<<<fb, 512, 0, stream>>>(Xb, cnt, b0, b1, WB, bd, bc, bs, out, N);
}